// Round 8
// baseline (159.530 us; speedup 1.0000x reference)
//
#include <hip/hip_runtime.h>
#include <math.h>

// Problem dims (fixed by setup_inputs): B=1024, D=256, H=1024
#define Bsz 1024
#define Dsz 256
#define Hsz 1024

typedef unsigned short u16;
typedef __bf16 bf16x8 __attribute__((ext_vector_type(8)));
typedef float  f32x4  __attribute__((ext_vector_type(4)));

__device__ __forceinline__ float bf2f(u16 u) {
  unsigned v = ((unsigned)u) << 16;
  return __builtin_bit_cast(float, v);
}
__device__ __forceinline__ u16 f2bf(float f) {
  unsigned u = __builtin_bit_cast(unsigned, f);
  u += 0x7FFFu + ((u >> 16) & 1u);  // round-to-nearest-even
  return (u16)(u >> 16);
}

constexpr int LS = 72;  // LDS row stride (bf16): 144B -> staggered banks

__device__ __forceinline__ bf16x8 frag(const u16* __restrict__ s, int row, int off) {
  union { uint4 u; bf16x8 b; } cv;
  cv.u = *reinterpret_cast<const uint4*>(&s[row * LS + off]);
  return cv.b;
}
#define MFMA __builtin_amdgcn_mfma_f32_16x16x32_bf16

// ---------------------------------------------------------------------------
// prep: casts/transposes + ldj/reg zeroing (896 blocks)
// ---------------------------------------------------------------------------
__device__ __forceinline__ void cast_chunk(const float* __restrict__ in,
                                           u16* __restrict__ out, int b, int t) {
  const int i = b * 256 + t;
  const float4 v = reinterpret_cast<const float4*>(in)[i];
  ushort4 o;
  o.x = f2bf(v.x); o.y = f2bf(v.y); o.z = f2bf(v.z); o.w = f2bf(v.w);
  *reinterpret_cast<ushort4*>(&out[(size_t)i * 4]) = o;
}

__device__ __forceinline__ void tr_tile(float (*tl)[65], const float* __restrict__ in,
                                        u16* __restrict__ out, int R, int C,
                                        int c0, int r0, int t) {
#pragma unroll
  for (int p = 0; p < 4; ++p) {
    const int r = p * 16 + (t >> 4);
    const int c = (t & 15) * 4;
    const float4 v = *reinterpret_cast<const float4*>(&in[(size_t)(r0 + r) * C + c0 + c]);
    tl[r][c] = v.x; tl[r][c + 1] = v.y; tl[r][c + 2] = v.z; tl[r][c + 3] = v.w;
  }
  __syncthreads();
#pragma unroll
  for (int p = 0; p < 4; ++p) {
    const int a = p * 16 + (t >> 4);
    const int b4 = (t & 15) * 4;
    ushort4 o;
    o.x = f2bf(tl[b4 + 0][a]); o.y = f2bf(tl[b4 + 1][a]);
    o.z = f2bf(tl[b4 + 2][a]); o.w = f2bf(tl[b4 + 3][a]);
    *reinterpret_cast<ushort4*>(&out[(size_t)(c0 + a) * R + r0 + b4]) = o;
  }
}

__global__ __launch_bounds__(256) void prep(const float* __restrict__ x,
                                            const float* __restrict__ W1,
                                            const float* __restrict__ W2,
                                            const float* __restrict__ W3,
                                            u16* __restrict__ xb,
                                            u16* __restrict__ W3b,
                                            u16* __restrict__ W1bT,
                                            u16* __restrict__ W2bT,
                                            u16* __restrict__ W3bT,
                                            float* __restrict__ ldj) {
  __shared__ float tl[64][65];
  const int b = blockIdx.x, t = threadIdx.x;
  if (b == 0) {
    for (int i = t; i < 2048; i += 256) ldj[i] = 0.0f;
  }
  if (b < 256) {
    cast_chunk(x, xb, b, t);
  } else if (b < 512) {
    cast_chunk(W3, W3b, b - 256, t);
  } else if (b < 576) {
    const int tb = b - 512;  // W1 [D][H] -> W1bT [H][D]
    tr_tile(tl, W1, W1bT, Dsz, Hsz, (tb & 15) * 64, (tb >> 4) * 64, t);
  } else if (b < 832) {
    const int tb = b - 576;  // W2 [H][H] -> W2bT [H][H]
    tr_tile(tl, W2, W2bT, Hsz, Hsz, (tb & 15) * 64, (tb >> 4) * 64, t);
  } else {
    const int tb = b - 832;  // W3 [H][D] -> W3bT [D][H]
    tr_tile(tl, W3, W3bT, Hsz, Dsz, (tb & 3) * 64, (tb >> 2) * 64, t);
  }
}

// ---------------------------------------------------------------------------
// phaseBB (256 blocks): fused k1+k2, sharing the staged W1bT (B) tile.
//   acc1: H1[b,i]  = xb  @ W1bT^T -> tanh(+b1+ts*tW) -> H1b
//   acc2: M[j,i]   = W3b @ W1bT^T -> * W2bT[j][i]    -> AmatT
// ---------------------------------------------------------------------------
__global__ __launch_bounds__(256) void phaseBB(const u16* __restrict__ xb,
                                               const u16* __restrict__ W3b,
                                               const u16* __restrict__ W1bT,
                                               const u16* __restrict__ W2bT,
                                               u16* __restrict__ H1b,
                                               u16* __restrict__ AmatT,
                                               const float* __restrict__ b1,
                                               const float* __restrict__ tW,
                                               const float* __restrict__ tptr) {
  __shared__ u16 A1s[64 * LS];
  __shared__ u16 A2s[64 * LS];
  __shared__ u16 Bs[64 * LS];
  const int t = threadIdx.x;
  const int lane = t & 63, wid = t >> 6;
  const int bz = ((blockIdx.x & 7) << 5) + (blockIdx.x >> 3);  // XCD swizzle (256%8==0)
  const int row0 = (bz >> 4) * 64, col0 = (bz & 15) * 64;

  const int sm = t >> 2, sq = t & 3;
  const size_t ab = (size_t)(row0 + sm) * Dsz + sq * 8;
  const size_t bb = (size_t)(col0 + sm) * Dsz + sq * 8;

  uint4 a1r[2], a2r[2], br[2];
  auto load_regs = [&](int k0) {
    a1r[0] = *reinterpret_cast<const uint4*>(&xb[ab + k0]);
    a1r[1] = *reinterpret_cast<const uint4*>(&xb[ab + k0 + 32]);
    a2r[0] = *reinterpret_cast<const uint4*>(&W3b[ab + k0]);
    a2r[1] = *reinterpret_cast<const uint4*>(&W3b[ab + k0 + 32]);
    br[0]  = *reinterpret_cast<const uint4*>(&W1bT[bb + k0]);
    br[1]  = *reinterpret_cast<const uint4*>(&W1bT[bb + k0 + 32]);
  };
  auto store_lds = [&]() {
    const int o = sm * LS + sq * 8;
#pragma unroll
    for (int c = 0; c < 2; ++c) {
      *reinterpret_cast<uint4*>(&A1s[o + c * 32]) = a1r[c];
      *reinterpret_cast<uint4*>(&A2s[o + c * 32]) = a2r[c];
      *reinterpret_cast<uint4*>(&Bs[o + c * 32])  = br[c];
    }
  };

  f32x4 acc1[2][2] = {}, acc2[2][2] = {};
  const int mo = (wid >> 1) * 32, no = (wid & 1) * 32;
  const int fr = lane & 15, fg = lane >> 4;

  load_regs(0);
  for (int it = 0; it < Dsz / 64; ++it) {
    __syncthreads();
    store_lds();
    if (it + 1 < Dsz / 64) load_regs((it + 1) << 6);
    __syncthreads();
#pragma unroll
    for (int ks = 0; ks < 64; ks += 32) {
      const int off = ks + fg * 8;
      const bf16x8 a10 = frag(A1s, mo + fr, off), a11 = frag(A1s, mo + 16 + fr, off);
      const bf16x8 a20 = frag(A2s, mo + fr, off), a21 = frag(A2s, mo + 16 + fr, off);
      const bf16x8 b0  = frag(Bs,  no + fr, off), b1v = frag(Bs,  no + 16 + fr, off);
      acc1[0][0] = MFMA(a10, b0,  acc1[0][0], 0, 0, 0);
      acc1[0][1] = MFMA(a10, b1v, acc1[0][1], 0, 0, 0);
      acc1[1][0] = MFMA(a11, b0,  acc1[1][0], 0, 0, 0);
      acc1[1][1] = MFMA(a11, b1v, acc1[1][1], 0, 0, 0);
      acc2[0][0] = MFMA(a20, b0,  acc2[0][0], 0, 0, 0);
      acc2[0][1] = MFMA(a20, b1v, acc2[0][1], 0, 0, 0);
      acc2[1][0] = MFMA(a21, b0,  acc2[1][0], 0, 0, 0);
      acc2[1][1] = MFMA(a21, b1v, acc2[1][1], 0, 0, 0);
    }
  }

  // C/D layout: col = lane&15, row = (lane>>4)*4 + reg
  const int cr = mo + fg * 4, cc = no + fr;
  const float ts = tptr[0];
#pragma unroll
  for (int ni = 0; ni < 2; ++ni) {
    const int col = col0 + cc + ni * 16;
    const float add = b1[col] + ts * tW[col];
#pragma unroll
    for (int mi = 0; mi < 2; ++mi)
#pragma unroll
      for (int r = 0; r < 4; ++r) {
        const int row = row0 + cr + mi * 16 + r;
        // k1: H1
        H1b[(size_t)row * Hsz + col] = f2bf(tanhf(acc1[mi][ni][r] + add));
        // k2: AmatT[j][i] = W2bT[j][i] * M[j][i]
        const float w2 = bf2f(W2bT[(size_t)row * Hsz + col]);
        AmatT[(size_t)row * Hsz + col] = f2bf(w2 * acc2[mi][ni][r]);
      }
  }
}

// ---------------------------------------------------------------------------
// phaseCD (256 blocks): fused k3+k5, sharing the staged H1b (A) tile.
//   acc1: Z[b,j] = H1b @ W2bT^T          (raw A)
//   acc2: U[b,j] = (1-H1b^2) @ AmatT^T   (transformed A, staged from same regs)
//   epilogue: h2 = tanh(Z + b2) -> H2b;  ldj[b] += sum_j U*(1-h2^2)  (f32 d2!)
// ---------------------------------------------------------------------------
__global__ __launch_bounds__(256) void phaseCD(const u16* __restrict__ H1b,
                                               const u16* __restrict__ W2bT,
                                               const u16* __restrict__ AmatT,
                                               u16* __restrict__ H2b,
                                               float* __restrict__ ldj,
                                               const float* __restrict__ b2) {
  __shared__ u16 Ars[64 * LS];
  __shared__ u16 Ads[64 * LS];
  __shared__ u16 B1s[64 * LS];
  __shared__ u16 B2s[64 * LS];
  __shared__ float sred[64][33];
  const int t = threadIdx.x;
  const int lane = t & 63, wid = t >> 6;
  const int bz = ((blockIdx.x & 7) << 5) + (blockIdx.x >> 3);
  const int row0 = (bz >> 4) * 64, col0 = (bz & 15) * 64;

  const int sm = t >> 2, sq = t & 3;
  const size_t ab = (size_t)(row0 + sm) * Hsz + sq * 8;
  const size_t bb = (size_t)(col0 + sm) * Hsz + sq * 8;

  uint4 ar[2], b1r[2], b2r[2];
  auto load_regs = [&](int k0) {
    ar[0]  = *reinterpret_cast<const uint4*>(&H1b[ab + k0]);
    ar[1]  = *reinterpret_cast<const uint4*>(&H1b[ab + k0 + 32]);
    b1r[0] = *reinterpret_cast<const uint4*>(&W2bT[bb + k0]);
    b1r[1] = *reinterpret_cast<const uint4*>(&W2bT[bb + k0 + 32]);
    b2r[0] = *reinterpret_cast<const uint4*>(&AmatT[bb + k0]);
    b2r[1] = *reinterpret_cast<const uint4*>(&AmatT[bb + k0 + 32]);
  };
  auto sq_tr = [&](uint4 v) -> uint4 {
    u16* p = reinterpret_cast<u16*>(&v);
    uint4 o; u16* po = reinterpret_cast<u16*>(&o);
#pragma unroll
    for (int i = 0; i < 8; ++i) { const float h = bf2f(p[i]); po[i] = f2bf(1.0f - h * h); }
    return o;
  };
  auto store_lds = [&]() {
    const int o = sm * LS + sq * 8;
#pragma unroll
    for (int c = 0; c < 2; ++c) {
      *reinterpret_cast<uint4*>(&Ars[o + c * 32]) = ar[c];
      *reinterpret_cast<uint4*>(&Ads[o + c * 32]) = sq_tr(ar[c]);
      *reinterpret_cast<uint4*>(&B1s[o + c * 32]) = b1r[c];
      *reinterpret_cast<uint4*>(&B2s[o + c * 32]) = b2r[c];
    }
  };

  f32x4 acc1[2][2] = {}, acc2[2][2] = {};
  const int mo = (wid >> 1) * 32, no = (wid & 1) * 32;
  const int fr = lane & 15, fg = lane >> 4;

  load_regs(0);
  for (int it = 0; it < Hsz / 64; ++it) {
    __syncthreads();
    store_lds();
    if (it + 1 < Hsz / 64) load_regs((it + 1) << 6);
    __syncthreads();
#pragma unroll
    for (int ks = 0; ks < 64; ks += 32) {
      const int off = ks + fg * 8;
      const bf16x8 x0 = frag(Ars, mo + fr, off), x1 = frag(Ars, mo + 16 + fr, off);
      const bf16x8 d0 = frag(Ads, mo + fr, off), d1 = frag(Ads, mo + 16 + fr, off);
      const bf16x8 w0 = frag(B1s, no + fr, off), w1 = frag(B1s, no + 16 + fr, off);
      const bf16x8 m0 = frag(B2s, no + fr, off), m1 = frag(B2s, no + 16 + fr, off);
      acc1[0][0] = MFMA(x0, w0, acc1[0][0], 0, 0, 0);
      acc1[0][1] = MFMA(x0, w1, acc1[0][1], 0, 0, 0);
      acc1[1][0] = MFMA(x1, w0, acc1[1][0], 0, 0, 0);
      acc1[1][1] = MFMA(x1, w1, acc1[1][1], 0, 0, 0);
      acc2[0][0] = MFMA(d0, m0, acc2[0][0], 0, 0, 0);
      acc2[0][1] = MFMA(d0, m1, acc2[0][1], 0, 0, 0);
      acc2[1][0] = MFMA(d1, m0, acc2[1][0], 0, 0, 0);
      acc2[1][1] = MFMA(d1, m1, acc2[1][1], 0, 0, 0);
    }
  }

  const int cr = mo + fg * 4, cc = no + fr;
#pragma unroll
  for (int mi = 0; mi < 2; ++mi)
#pragma unroll
    for (int r = 0; r < 4; ++r) {
      float s = 0.f;
#pragma unroll
      for (int ni = 0; ni < 2; ++ni) {
        const int col = col0 + cc + ni * 16;
        const int row = row0 + cr + mi * 16 + r;
        const float h = tanhf(acc1[mi][ni][r] + b2[col]);
        H2b[(size_t)row * Hsz + col] = f2bf(h);
        s += acc2[mi][ni][r] * (1.0f - h * h);
      }
      sred[cr + mi * 16 + r][(wid & 1) * 16 + fr] = s;
    }
  __syncthreads();
  if (t < 64) {
    float s = 0.f;
#pragma unroll
    for (int u = 0; u < 32; ++u) s += sred[t][u];
    atomicAdd(&ldj[row0 + t], s);
  }
}

// ---------------------------------------------------------------------------
// phaseE (64 blocks): k4 dx = H2 @ W3 + b3
// ---------------------------------------------------------------------------
__global__ __launch_bounds__(256) void phaseE(const u16* __restrict__ H2b,
                                              const u16* __restrict__ W3bT,
                                              float* __restrict__ dx,
                                              const float* __restrict__ b3) {
  __shared__ u16 As[64 * LS];
  __shared__ u16 Bs[64 * LS];
  const int t = threadIdx.x;
  const int lane = t & 63, wid = t >> 6;
  const int bz = ((blockIdx.x & 7) << 3) + (blockIdx.x >> 3);  // 64%8==0
  const int row0 = (bz >> 2) * 64, col0 = (bz & 3) * 64;

  const int sm = t >> 2, sq = t & 3;
  const size_t ab = (size_t)(row0 + sm) * Hsz + sq * 8;
  const size_t bb = (size_t)(col0 + sm) * Hsz + sq * 8;

  uint4 ar[2], br[2];
  auto load_regs = [&](int k0) {
    ar[0] = *reinterpret_cast<const uint4*>(&H2b[ab + k0]);
    ar[1] = *reinterpret_cast<const uint4*>(&H2b[ab + k0 + 32]);
    br[0] = *reinterpret_cast<const uint4*>(&W3bT[bb + k0]);
    br[1] = *reinterpret_cast<const uint4*>(&W3bT[bb + k0 + 32]);
  };
  auto store_lds = [&]() {
    const int o = sm * LS + sq * 8;
#pragma unroll
    for (int c = 0; c < 2; ++c) {
      *reinterpret_cast<uint4*>(&As[o + c * 32]) = ar[c];
      *reinterpret_cast<uint4*>(&Bs[o + c * 32]) = br[c];
    }
  };

  f32x4 acc[2][2] = {};
  const int mo = (wid >> 1) * 32, no = (wid & 1) * 32;
  const int fr = lane & 15, fg = lane >> 4;

  load_regs(0);
  for (int it = 0; it < Hsz / 64; ++it) {
    __syncthreads();
    store_lds();
    if (it + 1 < Hsz / 64) load_regs((it + 1) << 6);
    __syncthreads();
#pragma unroll
    for (int ks = 0; ks < 64; ks += 32) {
      const int off = ks + fg * 8;
      const bf16x8 a0 = frag(As, mo + fr, off), a1 = frag(As, mo + 16 + fr, off);
      const bf16x8 b0 = frag(Bs, no + fr, off), b1v = frag(Bs, no + 16 + fr, off);
      acc[0][0] = MFMA(a0, b0,  acc[0][0], 0, 0, 0);
      acc[0][1] = MFMA(a0, b1v, acc[0][1], 0, 0, 0);
      acc[1][0] = MFMA(a1, b0,  acc[1][0], 0, 0, 0);
      acc[1][1] = MFMA(a1, b1v, acc[1][1], 0, 0, 0);
    }
  }

  const int cr = mo + fg * 4, cc = no + fr;
#pragma unroll
  for (int ni = 0; ni < 2; ++ni) {
    const int col = col0 + cc + ni * 16;
    const float add = b3[col];
#pragma unroll
    for (int mi = 0; mi < 2; ++mi)
#pragma unroll
      for (int r = 0; r < 4; ++r) {
        const int row = row0 + cr + mi * 16 + r;
        dx[(size_t)row * Dsz + col] = acc[mi][ni][r] + add;
      }
  }
}

// ---------------------------------------------------------------------------
// Launch: 4 dispatches.
// ldj[b] = sum_{i,j} d1[b,i]*(W2.*N)[i,j]*d2[b,j],  N = (W3@W1)^T.
// ---------------------------------------------------------------------------
extern "C" void kernel_launch(void* const* d_in, const int* in_sizes, int n_in,
                              void* d_out, int out_size, void* d_ws, size_t ws_size,
                              hipStream_t stream) {
  const float* x  = (const float*)d_in[0];
  const float* t  = (const float*)d_in[1];
  const float* W1 = (const float*)d_in[4];
  const float* b1 = (const float*)d_in[5];
  const float* tW = (const float*)d_in[6];
  const float* W2 = (const float*)d_in[7];
  const float* b2 = (const float*)d_in[8];
  const float* W3 = (const float*)d_in[9];
  const float* b3 = (const float*)d_in[10];

  float* out = (float*)d_out;
  float* dx  = out;                      // [B,D]
  float* ldj = out + (size_t)Bsz * Dsz;  // [B], then reg [B]

  u16* w = (u16*)d_ws;
  u16* xb    = w;                    // [B][D]    262144
  u16* W1bT  = xb    + 262144;       // [H][D]    (= W1^T)
  u16* W3b   = W1bT  + 262144;       // [H][D]
  u16* W3bT  = W3b   + 262144;       // [D][H]    (= W3^T)
  u16* W2bT  = W3bT  + 262144;       // [H][H]    (= W2^T)
  u16* AmatT = W2bT  + 1048576;      // [H][H]
  u16* H1b   = AmatT + 1048576;      // [B][H]
  u16* H2b   = H1b   + 1048576;      // [B][H]    (10.5 MB total)

  const dim3 blk(256);
  prep   <<<dim3(896), blk, 0, stream>>>(x, W1, W2, W3, xb, W3b, W1bT, W2bT, W3bT, ldj);
  phaseBB<<<dim3(256), blk, 0, stream>>>(xb, W3b, W1bT, W2bT, H1b, AmatT, b1, tW, t);
  phaseCD<<<dim3(256), blk, 0, stream>>>(H1b, W2bT, AmatT, H2b, ldj, b2);
  phaseE <<<dim3(64),  blk, 0, stream>>>(H2b, W3bT, dx, b3);
}

// Round 9
// 140.796 us; speedup vs baseline: 1.1331x; 1.1331x over previous
//
#include <hip/hip_runtime.h>
#include <math.h>

// Problem dims (fixed by setup_inputs): B=1024, D=256, H=1024
#define Bsz 1024
#define Dsz 256
#define Hsz 1024

typedef unsigned short u16;
typedef __bf16 bf16x8 __attribute__((ext_vector_type(8)));
typedef float  f32x4  __attribute__((ext_vector_type(4)));

__device__ __forceinline__ float bf2f(u16 u) {
  unsigned v = ((unsigned)u) << 16;
  return __builtin_bit_cast(float, v);
}
__device__ __forceinline__ u16 f2bf(float f) {
  unsigned u = __builtin_bit_cast(unsigned, f);
  u += 0x7FFFu + ((u >> 16) & 1u);  // round-to-nearest-even
  return (u16)(u >> 16);
}

constexpr int LS = 72;  // LDS row stride (bf16): 144B -> staggered banks

__device__ __forceinline__ bf16x8 frag(const u16* __restrict__ s, int row, int off) {
  union { uint4 u; bf16x8 b; } cv;
  cv.u = *reinterpret_cast<const uint4*>(&s[row * LS + off]);
  return cv.b;
}
#define MFMA __builtin_amdgcn_mfma_f32_16x16x32_bf16

// ---------------------------------------------------------------------------
// prep: casts/transposes + ldj/reg zeroing (896 blocks)
// ---------------------------------------------------------------------------
__device__ __forceinline__ void cast_chunk(const float* __restrict__ in,
                                           u16* __restrict__ out, int b, int t) {
  const int i = b * 256 + t;
  const float4 v = reinterpret_cast<const float4*>(in)[i];
  ushort4 o;
  o.x = f2bf(v.x); o.y = f2bf(v.y); o.z = f2bf(v.z); o.w = f2bf(v.w);
  *reinterpret_cast<ushort4*>(&out[(size_t)i * 4]) = o;
}

__device__ __forceinline__ void tr_tile(float (*tl)[65], const float* __restrict__ in,
                                        u16* __restrict__ out, int R, int C,
                                        int c0, int r0, int t) {
#pragma unroll
  for (int p = 0; p < 4; ++p) {
    const int r = p * 16 + (t >> 4);
    const int c = (t & 15) * 4;
    const float4 v = *reinterpret_cast<const float4*>(&in[(size_t)(r0 + r) * C + c0 + c]);
    tl[r][c] = v.x; tl[r][c + 1] = v.y; tl[r][c + 2] = v.z; tl[r][c + 3] = v.w;
  }
  __syncthreads();
#pragma unroll
  for (int p = 0; p < 4; ++p) {
    const int a = p * 16 + (t >> 4);
    const int b4 = (t & 15) * 4;
    ushort4 o;
    o.x = f2bf(tl[b4 + 0][a]); o.y = f2bf(tl[b4 + 1][a]);
    o.z = f2bf(tl[b4 + 2][a]); o.w = f2bf(tl[b4 + 3][a]);
    *reinterpret_cast<ushort4*>(&out[(size_t)(c0 + a) * R + r0 + b4]) = o;
  }
}

__global__ __launch_bounds__(256) void prep(const float* __restrict__ x,
                                            const float* __restrict__ W1,
                                            const float* __restrict__ W2,
                                            const float* __restrict__ W3,
                                            u16* __restrict__ xb,
                                            u16* __restrict__ W3b,
                                            u16* __restrict__ W1bT,
                                            u16* __restrict__ W2bT,
                                            u16* __restrict__ W3bT,
                                            float* __restrict__ ldj) {
  __shared__ float tl[64][65];
  const int b = blockIdx.x, t = threadIdx.x;
  if (b == 0) {
    for (int i = t; i < 2048; i += 256) ldj[i] = 0.0f;
  }
  if (b < 256) {
    cast_chunk(x, xb, b, t);
  } else if (b < 512) {
    cast_chunk(W3, W3b, b - 256, t);
  } else if (b < 576) {
    const int tb = b - 512;  // W1 [D][H] -> W1bT [H][D]
    tr_tile(tl, W1, W1bT, Dsz, Hsz, (tb & 15) * 64, (tb >> 4) * 64, t);
  } else if (b < 832) {
    const int tb = b - 576;  // W2 [H][H] -> W2bT [H][H]
    tr_tile(tl, W2, W2bT, Hsz, Hsz, (tb & 15) * 64, (tb >> 4) * 64, t);
  } else {
    const int tb = b - 832;  // W3 [H][D] -> W3bT [D][H]
    tr_tile(tl, W3, W3bT, Hsz, Dsz, (tb & 3) * 64, (tb >> 2) * 64, t);
  }
}

// ---------------------------------------------------------------------------
// MFMA GEMM body: C[ROWS x 64 tile] = A[M][K] * Bt[N][K]^T, bf16, f32 accum.
// ROWS=64: 4 waves in 2x2, 32x32 quadrants (orig, measured-good).
// ROWS=32: 4 waves in 2x2, 16x32 quadrants -> 2x the blocks per phase (TLP).
// BK=64, reg-prefetch of next tile. LDS rows padded to 72 bf16.
// SQA: h -> 1-h*h while staging (d1 from H1b without a separate buffer).
// ---------------------------------------------------------------------------
enum { EPI_H1 = 0, EPI_AMAT = 1, EPI_H2 = 2, EPI_DX = 3, EPI_TRACE = 4 };

template <int EPI, bool SQA, int ROWS>
__device__ __forceinline__ void gemm_body(
    int row0, int col0,
    u16* __restrict__ As, u16* __restrict__ Bs, float (*sred)[33],
    const u16* __restrict__ A, const u16* __restrict__ Bt,
    int K, int ldo,
    float* __restrict__ fout, u16* __restrict__ bout,
    const u16* __restrict__ aux,
    const float* __restrict__ v1, const float* __restrict__ v2,
    const float* __restrict__ tptr) {
  const int t = threadIdx.x;
  const int lane = t & 63, wid = t >> 6;

  // B staging (always 64 rows): row sm, 16B chunks at sq*8 and +32
  const int sm = t >> 2, sq = t & 3;
  const size_t b_base = (size_t)(col0 + sm) * K + sq * 8;
  // A staging: ROWS=64 like B; ROWS=32: row t>>3, single 16B chunk at (t&7)*8
  const int am = (ROWS == 64) ? sm : (t >> 3);
  const int aq = (ROWS == 64) ? sq : (t & 7);
  const size_t a_base = (size_t)(row0 + am) * K + aq * 8;

  uint4 ar[2], br[2];
  auto load_regs = [&](int k0) {
    ar[0] = *reinterpret_cast<const uint4*>(&A[a_base + k0]);
    if (ROWS == 64) ar[1] = *reinterpret_cast<const uint4*>(&A[a_base + k0 + 32]);
    br[0] = *reinterpret_cast<const uint4*>(&Bt[b_base + k0]);
    br[1] = *reinterpret_cast<const uint4*>(&Bt[b_base + k0 + 32]);
  };
  auto sq_tr = [&](uint4 v) -> uint4 {
    u16* p = reinterpret_cast<u16*>(&v);
    uint4 o; u16* po = reinterpret_cast<u16*>(&o);
#pragma unroll
    for (int i = 0; i < 8; ++i) { const float h = bf2f(p[i]); po[i] = f2bf(1.0f - h * h); }
    return o;
  };
  auto store_lds = [&]() {
    const int ob = sm * LS + sq * 8;
    *reinterpret_cast<uint4*>(&Bs[ob +  0]) = br[0];
    *reinterpret_cast<uint4*>(&Bs[ob + 32]) = br[1];
    const int oa = am * LS + aq * 8;
    *reinterpret_cast<uint4*>(&As[oa]) = SQA ? sq_tr(ar[0]) : ar[0];
    if (ROWS == 64)
      *reinterpret_cast<uint4*>(&As[oa + 32]) = SQA ? sq_tr(ar[1]) : ar[1];
  };

  constexpr int MI = ROWS / 32;  // row-frags per wave: 2 (64) or 1 (32)
  f32x4 acc[MI][2] = {};
  const int mo = (wid >> 1) * (ROWS / 2), no = (wid & 1) * 32;
  const int fr = lane & 15, fg = lane >> 4;

  const int NK = K >> 6;
  load_regs(0);
  for (int it = 0; it < NK; ++it) {
    __syncthreads();          // previous compute done; LDS free
    store_lds();
    if (it + 1 < NK) load_regs((it + 1) << 6);
    __syncthreads();          // tile visible
#pragma unroll
    for (int ks = 0; ks < 64; ks += 32) {
      const int off = ks + fg * 8;
      const bf16x8 b0  = frag(Bs, no + fr, off);
      const bf16x8 b1v = frag(Bs, no + 16 + fr, off);
#pragma unroll
      for (int mi = 0; mi < MI; ++mi) {
        const bf16x8 a = frag(As, mo + mi * 16 + fr, off);
        acc[mi][0] = MFMA(a, b0,  acc[mi][0], 0, 0, 0);
        acc[mi][1] = MFMA(a, b1v, acc[mi][1], 0, 0, 0);
      }
    }
  }

  // C/D layout (m89-verified): col = lane&15, row = (lane>>4)*4 + reg
  const int cr = mo + fg * 4;  // + mi*16 + r  (block-local row)
  const int cc = no + fr;      // + ni*16      (block-local col)

  if (EPI == EPI_H1) {
    const float ts = tptr[0];
#pragma unroll
    for (int ni = 0; ni < 2; ++ni) {
      const int col = col0 + cc + ni * 16;
      const float add = v1[col] + ts * v2[col];
#pragma unroll
      for (int mi = 0; mi < MI; ++mi)
#pragma unroll
        for (int r = 0; r < 4; ++r) {
          const int row = row0 + cr + mi * 16 + r;
          bout[(size_t)row * Hsz + col] = f2bf(tanhf(acc[mi][ni][r] + add));
        }
    }
  } else if (EPI == EPI_AMAT) {
#pragma unroll
    for (int mi = 0; mi < MI; ++mi)
#pragma unroll
      for (int ni = 0; ni < 2; ++ni)
#pragma unroll
        for (int r = 0; r < 4; ++r) {
          const int row = row0 + cr + mi * 16 + r;
          const int col = col0 + cc + ni * 16;
          const float w2 = bf2f(aux[(size_t)row * Hsz + col]);  // W2bT[j][i] = W2[i][j]
          bout[(size_t)row * Hsz + col] = f2bf(w2 * acc[mi][ni][r]);
        }
  } else if (EPI == EPI_H2) {
#pragma unroll
    for (int ni = 0; ni < 2; ++ni) {
      const int col = col0 + cc + ni * 16;
      const float add = v1[col];
#pragma unroll
      for (int mi = 0; mi < MI; ++mi)
#pragma unroll
        for (int r = 0; r < 4; ++r) {
          const int row = row0 + cr + mi * 16 + r;
          bout[(size_t)row * Hsz + col] = f2bf(tanhf(acc[mi][ni][r] + add));
        }
    }
  } else if (EPI == EPI_DX) {
#pragma unroll
    for (int ni = 0; ni < 2; ++ni) {
      const int col = col0 + cc + ni * 16;
      const float add = v1[col];
#pragma unroll
      for (int mi = 0; mi < MI; ++mi)
#pragma unroll
        for (int r = 0; r < 4; ++r) {
          const int row = row0 + cr + mi * 16 + r;
          fout[(size_t)row * ldo + col] = acc[mi][ni][r] + add;
        }
    }
  } else {  // EPI_TRACE: s = sum_j U[b,j]*(1-h2[b,j]^2) ; atomicAdd per row
#pragma unroll
    for (int mi = 0; mi < MI; ++mi)
#pragma unroll
      for (int r = 0; r < 4; ++r) {
        const int row = row0 + cr + mi * 16 + r;
        float s = 0.f;
#pragma unroll
        for (int ni = 0; ni < 2; ++ni) {
          const int col = col0 + cc + ni * 16;
          const float h2 = bf2f(aux[(size_t)row * Hsz + col]);
          s += acc[mi][ni][r] * (1.0f - h2 * h2);
        }
        sred[cr + mi * 16 + r][(wid & 1) * 16 + fr] = s;
      }
    __syncthreads();
    if (t < ROWS) {
      float s = 0.f;
#pragma unroll
      for (int u = 0; u < 32; ++u) s += sred[t][u];
      atomicAdd(&fout[row0 + t], s);
    }
  }
}

// ---------------------------------------------------------------------------
// Phase B (512 blocks, 64-row tiles): k1 (b<256) + k2 (b>=256)  [round-4]
// ---------------------------------------------------------------------------
__global__ __launch_bounds__(256) void phaseB(const u16* __restrict__ xb,
                                              const u16* __restrict__ W1bT,
                                              const u16* __restrict__ W3b,
                                              const u16* __restrict__ W2bT,
                                              u16* __restrict__ H1b,
                                              u16* __restrict__ AmatT,
                                              const float* __restrict__ b1,
                                              const float* __restrict__ tW,
                                              const float* __restrict__ t) {
  __shared__ u16 As[64 * LS];
  __shared__ u16 Bs[64 * LS];
  const int b = blockIdx.x;
  if (b < 256) {
    gemm_body<EPI_H1, false, 64>((b >> 4) * 64, (b & 15) * 64, As, Bs, nullptr,
                                 xb, W1bT, Dsz, Hsz, nullptr, H1b, nullptr, b1, tW, t);
  } else {
    const int c = b - 256;
    gemm_body<EPI_AMAT, false, 64>((c >> 4) * 64, (c & 15) * 64, As, Bs, nullptr,
                                   W3b, W1bT, Dsz, Hsz, nullptr, AmatT, W2bT,
                                   nullptr, nullptr, nullptr);
  }
}

// ---------------------------------------------------------------------------
// Phase C (512 blocks, 32-row tiles): k3 H2b = tanh(H1@W2 + b2), K=H
//   32x16 tile grid -> 2 blocks/CU (was 1) for latency overlap.
// ---------------------------------------------------------------------------
__global__ __launch_bounds__(256) void phaseC(const u16* __restrict__ H1b,
                                              const u16* __restrict__ W2bT,
                                              u16* __restrict__ H2b,
                                              const float* __restrict__ b2) {
  __shared__ u16 As[32 * LS];
  __shared__ u16 Bs[64 * LS];
  const int b = blockIdx.x;
  gemm_body<EPI_H2, false, 32>((b >> 4) * 32, (b & 15) * 64, As, Bs, nullptr,
                               H1b, W2bT, Hsz, Hsz, nullptr, H2b, nullptr, b2,
                               nullptr, nullptr);
}

// ---------------------------------------------------------------------------
// Phase D (640 blocks, 32-row tiles): k5 trace (512, heavy, first) + k4 (128)
// ---------------------------------------------------------------------------
__global__ __launch_bounds__(256) void phaseD(const u16* __restrict__ H1b,
                                              const u16* __restrict__ AmatT,
                                              const u16* __restrict__ H2b,
                                              const u16* __restrict__ W3bT,
                                              float* __restrict__ ldj,
                                              float* __restrict__ dx,
                                              const float* __restrict__ b3) {
  __shared__ u16 As[32 * LS];
  __shared__ u16 Bs[64 * LS];
  __shared__ float sred[32][33];
  const int b = blockIdx.x;
  if (b < 512) {
    gemm_body<EPI_TRACE, true, 32>((b >> 4) * 32, (b & 15) * 64, As, Bs, sred,
                                   H1b, AmatT, Hsz, 0, ldj, nullptr, H2b,
                                   nullptr, nullptr, nullptr);
  } else {
    const int c = b - 512;  // 128 blocks: 32 row-tiles x 4 col-tiles
    gemm_body<EPI_DX, false, 32>((c >> 2) * 32, (c & 3) * 64, As, Bs, nullptr,
                                 H2b, W3bT, Hsz, Dsz, dx, nullptr, nullptr, b3,
                                 nullptr, nullptr);
  }
}

// ---------------------------------------------------------------------------
// Launch: 4 dispatches.
// ldj[b] = sum_{i,j} d1[b,i]*(W2.*N)[i,j]*d2[b,j],  N = (W3@W1)^T.
// AmatT[j][i] = W2[i][j]*(W3@W1)[j][i] is k2's natural tile orientation AND
// the Bt layout k5 consumes. Same-B-panel blocks sit at stride 16 == 0 mod 8
// -> co-XCD L2 reuse with default dispatch; no swizzle.
// ---------------------------------------------------------------------------
extern "C" void kernel_launch(void* const* d_in, const int* in_sizes, int n_in,
                              void* d_out, int out_size, void* d_ws, size_t ws_size,
                              hipStream_t stream) {
  const float* x  = (const float*)d_in[0];
  const float* t  = (const float*)d_in[1];
  const float* W1 = (const float*)d_in[4];
  const float* b1 = (const float*)d_in[5];
  const float* tW = (const float*)d_in[6];
  const float* W2 = (const float*)d_in[7];
  const float* b2 = (const float*)d_in[8];
  const float* W3 = (const float*)d_in[9];
  const float* b3 = (const float*)d_in[10];

  float* out = (float*)d_out;
  float* dx  = out;                      // [B,D]
  float* ldj = out + (size_t)Bsz * Dsz;  // [B], then reg [B]

  u16* w = (u16*)d_ws;
  u16* xb    = w;                    // [B][D]    262144
  u16* W1bT  = xb    + 262144;       // [H][D]    (= W1^T)
  u16* W3b   = W1bT  + 262144;       // [H][D]
  u16* W3bT  = W3b   + 262144;       // [D][H]    (= W3^T)
  u16* W2bT  = W3bT  + 262144;       // [H][H]    (= W2^T)
  u16* AmatT = W2bT  + 1048576;      // [H][H]
  u16* H1b   = AmatT + 1048576;      // [B][H]
  u16* H2b   = H1b   + 1048576;      // [B][H]    (10.5 MB total)

  const dim3 blk(256);
  prep  <<<dim3(896), blk, 0, stream>>>(x, W1, W2, W3, xb, W3b, W1bT, W2bT, W3bT, ldj);
  phaseB<<<dim3(512), blk, 0, stream>>>(xb, W1bT, W3b, W2bT, H1b, AmatT, b1, tW, t);
  phaseC<<<dim3(512), blk, 0, stream>>>(H1b, W2bT, H2b, b2);
  phaseD<<<dim3(640), blk, 0, stream>>>(H1b, AmatT, H2b, W3bT, ldj, dx, b3);
}

// Round 13
// 131.788 us; speedup vs baseline: 1.2105x; 1.0684x over previous
//
#include <hip/hip_runtime.h>
#include <math.h>

// Problem dims (fixed by setup_inputs): B=1024, D=256, H=1024
#define Bsz 1024
#define Dsz 256
#define Hsz 1024

typedef unsigned short u16;
typedef __bf16 bf16x8 __attribute__((ext_vector_type(8)));
typedef float  f32x4  __attribute__((ext_vector_type(4)));

__device__ __forceinline__ float bf2f(u16 u) {
  unsigned v = ((unsigned)u) << 16;
  return __builtin_bit_cast(float, v);
}
__device__ __forceinline__ u16 f2bf(float f) {
  unsigned u = __builtin_bit_cast(unsigned, f);
  u += 0x7FFFu + ((u >> 16) & 1u);  // round-to-nearest-even
  return (u16)(u >> 16);
}

constexpr int LS = 72;  // LDS row stride (bf16): 144B -> staggered banks

__device__ __forceinline__ bf16x8 frag(const u16* __restrict__ s, int row, int off) {
  union { uint4 u; bf16x8 b; } cv;
  cv.u = *reinterpret_cast<const uint4*>(&s[row * LS + off]);
  return cv.b;
}
#define MFMA __builtin_amdgcn_mfma_f32_16x16x32_bf16

// ---------------------------------------------------------------------------
// prep: casts/transposes + reg/ldj zeroing (896 blocks)
// ---------------------------------------------------------------------------
__device__ __forceinline__ void cast_chunk(const float* __restrict__ in,
                                           u16* __restrict__ out, int b, int t) {
  const int i = b * 256 + t;
  const float4 v = reinterpret_cast<const float4*>(in)[i];
  ushort4 o;
  o.x = f2bf(v.x); o.y = f2bf(v.y); o.z = f2bf(v.z); o.w = f2bf(v.w);
  *reinterpret_cast<ushort4*>(&out[(size_t)i * 4]) = o;
}

__device__ __forceinline__ void tr_tile(float (*tl)[65], const float* __restrict__ in,
                                        u16* __restrict__ out, int R, int C,
                                        int c0, int r0, int t) {
#pragma unroll
  for (int p = 0; p < 4; ++p) {
    const int r = p * 16 + (t >> 4);
    const int c = (t & 15) * 4;
    const float4 v = *reinterpret_cast<const float4*>(&in[(size_t)(r0 + r) * C + c0 + c]);
    tl[r][c] = v.x; tl[r][c + 1] = v.y; tl[r][c + 2] = v.z; tl[r][c + 3] = v.w;
  }
  __syncthreads();
#pragma unroll
  for (int p = 0; p < 4; ++p) {
    const int a = p * 16 + (t >> 4);
    const int b4 = (t & 15) * 4;
    ushort4 o;
    o.x = f2bf(tl[b4 + 0][a]); o.y = f2bf(tl[b4 + 1][a]);
    o.z = f2bf(tl[b4 + 2][a]); o.w = f2bf(tl[b4 + 3][a]);
    *reinterpret_cast<ushort4*>(&out[(size_t)(c0 + a) * R + r0 + b4]) = o;
  }
}

__global__ __launch_bounds__(256) void prep(const float* __restrict__ x,
                                            const float* __restrict__ W1,
                                            const float* __restrict__ W2,
                                            const float* __restrict__ W3,
                                            u16* __restrict__ xb,
                                            u16* __restrict__ W3b,
                                            u16* __restrict__ W1bT,
                                            u16* __restrict__ W2bT,
                                            u16* __restrict__ W3bT,
                                            float* __restrict__ ldj) {
  __shared__ float tl[64][65];
  const int b = blockIdx.x, t = threadIdx.x;
  if (b == 0) {
    for (int i = t; i < 2048; i += 256) ldj[i] = 0.0f;  // ldj overwritten later; reg must be 0
  }
  if (b < 256) {
    cast_chunk(x, xb, b, t);
  } else if (b < 512) {
    cast_chunk(W3, W3b, b - 256, t);
  } else if (b < 576) {
    const int tb = b - 512;  // W1 [D][H] -> W1bT [H][D]
    tr_tile(tl, W1, W1bT, Dsz, Hsz, (tb & 15) * 64, (tb >> 4) * 64, t);
  } else if (b < 832) {
    const int tb = b - 576;  // W2 [H][H] -> W2bT [H][H]
    tr_tile(tl, W2, W2bT, Hsz, Hsz, (tb & 15) * 64, (tb >> 4) * 64, t);
  } else {
    const int tb = b - 832;  // W3 [H][D] -> W3bT [D][H]
    tr_tile(tl, W3, W3bT, Hsz, Dsz, (tb & 3) * 64, (tb >> 2) * 64, t);
  }
}

// ---------------------------------------------------------------------------
// MFMA GEMM body: C[64x64 tile] = A[M][K] * Bt[N][K]^T, bf16, f32 accum.
// 256 threads = 4 waves in 2x2; each wave a 32x32 quadrant (measured-best).
// BK=64, reg-prefetch of next tile. LDS rows padded to 72 bf16.
// SQA: h -> 1-h*h while staging (d1 from H1b without a separate buffer).
// ---------------------------------------------------------------------------
enum { EPI_H1 = 0, EPI_AMAT = 1, EPI_H2 = 2, EPI_DX = 3, EPI_U = 4 };

template <int EPI, bool SQA>
__device__ __forceinline__ void gemm_body(
    int row0, int col0,
    u16* __restrict__ As, u16* __restrict__ Bs,
    const u16* __restrict__ A, const u16* __restrict__ Bt,
    int K, int ldo,
    float* __restrict__ fout, u16* __restrict__ bout,
    const u16* __restrict__ aux,
    const float* __restrict__ v1, const float* __restrict__ v2,
    const float* __restrict__ tptr) {
  const int t = threadIdx.x;
  const int lane = t & 63, wid = t >> 6;

  const int sm = t >> 2, sq = t & 3;
  const size_t a_base = (size_t)(row0 + sm) * K + sq * 8;
  const size_t b_base = (size_t)(col0 + sm) * K + sq * 8;

  uint4 ar[2], br[2];
  auto load_regs = [&](int k0) {
    ar[0] = *reinterpret_cast<const uint4*>(&A[a_base + k0]);
    ar[1] = *reinterpret_cast<const uint4*>(&A[a_base + k0 + 32]);
    br[0] = *reinterpret_cast<const uint4*>(&Bt[b_base + k0]);
    br[1] = *reinterpret_cast<const uint4*>(&Bt[b_base + k0 + 32]);
  };
  auto sq_tr = [&](uint4 v) -> uint4 {
    u16* p = reinterpret_cast<u16*>(&v);
    uint4 o; u16* po = reinterpret_cast<u16*>(&o);
#pragma unroll
    for (int i = 0; i < 8; ++i) { const float h = bf2f(p[i]); po[i] = f2bf(1.0f - h * h); }
    return o;
  };
  auto store_lds = [&]() {
    const int o = sm * LS + sq * 8;
#pragma unroll
    for (int c = 0; c < 2; ++c) {
      *reinterpret_cast<uint4*>(&As[o + c * 32]) = SQA ? sq_tr(ar[c]) : ar[c];
      *reinterpret_cast<uint4*>(&Bs[o + c * 32]) = br[c];
    }
  };

  f32x4 acc[2][2] = {};
  const int mo = (wid >> 1) * 32, no = (wid & 1) * 32;
  const int fr = lane & 15, fg = lane >> 4;

  const int NK = K >> 6;
  load_regs(0);
  for (int it = 0; it < NK; ++it) {
    __syncthreads();          // previous compute done; LDS free
    store_lds();
    if (it + 1 < NK) load_regs((it + 1) << 6);
    __syncthreads();          // tile visible
#pragma unroll
    for (int ks = 0; ks < 64; ks += 32) {
      const int off = ks + fg * 8;
      const bf16x8 a0 = frag(As, mo + fr, off), a1 = frag(As, mo + 16 + fr, off);
      const bf16x8 b0 = frag(Bs, no + fr, off), b1v = frag(Bs, no + 16 + fr, off);
      acc[0][0] = MFMA(a0, b0,  acc[0][0], 0, 0, 0);
      acc[0][1] = MFMA(a0, b1v, acc[0][1], 0, 0, 0);
      acc[1][0] = MFMA(a1, b0,  acc[1][0], 0, 0, 0);
      acc[1][1] = MFMA(a1, b1v, acc[1][1], 0, 0, 0);
    }
  }

  // C/D layout (m89-verified): col = lane&15, row = (lane>>4)*4 + reg
  const int cr = mo + fg * 4;  // + mi*16 + r  (block-local row)
  const int cc = no + fr;      // + ni*16      (block-local col)

  if (EPI == EPI_H1) {
    const float ts = tptr[0];
#pragma unroll
    for (int ni = 0; ni < 2; ++ni) {
      const int col = col0 + cc + ni * 16;
      const float add = v1[col] + ts * v2[col];
#pragma unroll
      for (int mi = 0; mi < 2; ++mi)
#pragma unroll
        for (int r = 0; r < 4; ++r) {
          const int row = row0 + cr + mi * 16 + r;
          bout[(size_t)row * Hsz + col] = f2bf(tanhf(acc[mi][ni][r] + add));
        }
    }
  } else if (EPI == EPI_AMAT) {
#pragma unroll
    for (int mi = 0; mi < 2; ++mi)
#pragma unroll
      for (int ni = 0; ni < 2; ++ni)
#pragma unroll
        for (int r = 0; r < 4; ++r) {
          const int row = row0 + cr + mi * 16 + r;
          const int col = col0 + cc + ni * 16;
          const float w2 = bf2f(aux[(size_t)row * Hsz + col]);  // W2bT[j][i] = W2[i][j]
          bout[(size_t)row * Hsz + col] = f2bf(w2 * acc[mi][ni][r]);
        }
  } else if (EPI == EPI_H2) {
#pragma unroll
    for (int ni = 0; ni < 2; ++ni) {
      const int col = col0 + cc + ni * 16;
      const float add = v1[col];
#pragma unroll
      for (int mi = 0; mi < 2; ++mi)
#pragma unroll
        for (int r = 0; r < 4; ++r) {
          const int row = row0 + cr + mi * 16 + r;
          bout[(size_t)row * Hsz + col] = f2bf(tanhf(acc[mi][ni][r] + add));
        }
    }
  } else if (EPI == EPI_DX) {
#pragma unroll
    for (int ni = 0; ni < 2; ++ni) {
      const int col = col0 + cc + ni * 16;
      const float add = v1[col];
#pragma unroll
      for (int mi = 0; mi < 2; ++mi)
#pragma unroll
        for (int r = 0; r < 4; ++r) {
          const int row = row0 + cr + mi * 16 + r;
          fout[(size_t)row * ldo + col] = acc[mi][ni][r] + add;
        }
    }
  } else {  // EPI_U: raw f32 U tile to workspace
#pragma unroll
    for (int ni = 0; ni < 2; ++ni) {
      const int col = col0 + cc + ni * 16;
#pragma unroll
      for (int mi = 0; mi < 2; ++mi)
#pragma unroll
        for (int r = 0; r < 4; ++r) {
          const int row = row0 + cr + mi * 16 + r;
          fout[(size_t)row * Hsz + col] = acc[mi][ni][r];
        }
    }
  }
}

// ---------------------------------------------------------------------------
// Phase B (512 blocks): k1 (b<256) + k2 (b>=256)   [round-5 measured-best]
// ---------------------------------------------------------------------------
__global__ __launch_bounds__(256) void phaseB(const u16* __restrict__ xb,
                                              const u16* __restrict__ W1bT,
                                              const u16* __restrict__ W3b,
                                              const u16* __restrict__ W2bT,
                                              u16* __restrict__ H1b,
                                              u16* __restrict__ AmatT,
                                              const float* __restrict__ b1,
                                              const float* __restrict__ tW,
                                              const float* __restrict__ t) {
  __shared__ u16 As[64 * LS];
  __shared__ u16 Bs[64 * LS];
  const int b = blockIdx.x;
  if (b < 256) {
    gemm_body<EPI_H1, false>((b >> 4) * 64, (b & 15) * 64, As, Bs,
                             xb, W1bT, Dsz, Hsz, nullptr, H1b, nullptr, b1, tW, t);
  } else {
    const int c = b - 256;
    gemm_body<EPI_AMAT, false>((c >> 4) * 64, (c & 15) * 64, As, Bs,
                               W3b, W1bT, Dsz, Hsz, nullptr, AmatT, W2bT,
                               nullptr, nullptr, nullptr);
  }
}

// ---------------------------------------------------------------------------
// Phase CU (512 blocks): k3 H2b=tanh(H1@W2+b2) (b<256)  +  k5a U=d1@Amat
// (b>=256), CONCURRENT — k5a's GEMM needs only phaseB outputs. Each CU gets
// one k3 block + one k5a block: 2 independent barrier domains for latency
// overlap at full 64x64 tile efficiency.
// ---------------------------------------------------------------------------
__global__ __launch_bounds__(256) void phaseCU(const u16* __restrict__ H1b,
                                               const u16* __restrict__ W2bT,
                                               const u16* __restrict__ AmatT,
                                               u16* __restrict__ H2b,
                                               float* __restrict__ U,
                                               const float* __restrict__ b2) {
  __shared__ u16 As[64 * LS];
  __shared__ u16 Bs[64 * LS];
  const int b = blockIdx.x;
  if (b < 256) {
    gemm_body<EPI_H2, false>((b >> 4) * 64, (b & 15) * 64, As, Bs,
                             H1b, W2bT, Hsz, Hsz, nullptr, H2b, nullptr, b2,
                             nullptr, nullptr);
  } else {
    const int c = b - 256;
    gemm_body<EPI_U, true>((c >> 4) * 64, (c & 15) * 64, As, Bs,
                           H1b, AmatT, Hsz, Hsz, U, nullptr, nullptr,
                           nullptr, nullptr, nullptr);
  }
}

// ---------------------------------------------------------------------------
// Phase D (128 blocks): k4 dx (b<64)  +  k5b masked reduce (b>=64).
// k5b: ldj[row] = sum_j U[row][j] * (1 - h2[row][j]^2), direct store (no
// atomics). 64 blocks x 16 rows; 16 threads/row, coalesced float4 strides.
// ---------------------------------------------------------------------------
__global__ __launch_bounds__(256) void phaseD(const u16* __restrict__ H2b,
                                              const u16* __restrict__ W3bT,
                                              const float* __restrict__ U,
                                              float* __restrict__ dx,
                                              float* __restrict__ ldj,
                                              const float* __restrict__ b3) {
  const int b = blockIdx.x;
  if (b < 64) {
    __shared__ u16 As[64 * LS];
    __shared__ u16 Bs[64 * LS];
    gemm_body<EPI_DX, false>((b >> 2) * 64, (b & 3) * 64, As, Bs,
                             H2b, W3bT, Hsz, Dsz, dx, nullptr, nullptr, b3,
                             nullptr, nullptr);
  } else {
    __shared__ float sr[16][17];
    const int t = threadIdx.x;
    const int row = (b - 64) * 16 + (t >> 4);
    const int c0 = (t & 15) * 4;
    float s = 0.0f;
#pragma unroll
    for (int k = 0; k < 16; ++k) {
      const int c = c0 + k * 64;
      const float4 u4 = *reinterpret_cast<const float4*>(&U[(size_t)row * Hsz + c]);
      const ushort4 h4 = *reinterpret_cast<const ushort4*>(&H2b[(size_t)row * Hsz + c]);
      const float h0 = bf2f(h4.x), h1 = bf2f(h4.y), h2 = bf2f(h4.z), h3 = bf2f(h4.w);
      s += u4.x * (1.0f - h0 * h0) + u4.y * (1.0f - h1 * h1)
         + u4.z * (1.0f - h2 * h2) + u4.w * (1.0f - h3 * h3);
    }
    sr[t >> 4][t & 15] = s;
    __syncthreads();
    if (t < 16) {
      float tot = 0.0f;
#pragma unroll
      for (int u = 0; u < 16; ++u) tot += sr[t][u];
      ldj[(b - 64) * 16 + t] = tot;
    }
  }
}

// ---------------------------------------------------------------------------
// Launch: 4 dispatches.
// ldj[b] = sum_{i,j} d1[b,i]*(W2.*N)[i,j]*d2[b,j],  N = (W3@W1)^T.
// AmatT[j][i] = W2[i][j]*(W3@W1)[j][i] is k2's natural tile orientation AND
// the Bt layout k5a consumes.
// ---------------------------------------------------------------------------
extern "C" void kernel_launch(void* const* d_in, const int* in_sizes, int n_in,
                              void* d_out, int out_size, void* d_ws, size_t ws_size,
                              hipStream_t stream) {
  const float* x  = (const float*)d_in[0];
  const float* t  = (const float*)d_in[1];
  const float* W1 = (const float*)d_in[4];
  const float* b1 = (const float*)d_in[5];
  const float* tW = (const float*)d_in[6];
  const float* W2 = (const float*)d_in[7];
  const float* b2 = (const float*)d_in[8];
  const float* W3 = (const float*)d_in[9];
  const float* b3 = (const float*)d_in[10];

  float* out = (float*)d_out;
  float* dx  = out;                      // [B,D]
  float* ldj = out + (size_t)Bsz * Dsz;  // [B], then reg [B]

  u16* w = (u16*)d_ws;
  u16* xb    = w;                    // [B][D]    262144
  u16* W1bT  = xb    + 262144;       // [H][D]    (= W1^T)
  u16* W3b   = W1bT  + 262144;       // [H][D]
  u16* W3bT  = W3b   + 262144;       // [D][H]    (= W3^T)
  u16* W2bT  = W3bT  + 262144;       // [H][H]    (= W2^T)
  u16* AmatT = W2bT  + 1048576;      // [H][H]
  u16* H1b   = AmatT + 1048576;      // [B][H]
  u16* H2b   = H1b   + 1048576;      // [B][H]
  float* U   = (float*)(H2b + 1048576);  // [B][H] f32 (4 MB; 14.5 MB total)

  const dim3 blk(256);
  prep   <<<dim3(896), blk, 0, stream>>>(x, W1, W2, W3, xb, W3b, W1bT, W2bT, W3bT, ldj);
  phaseB <<<dim3(512), blk, 0, stream>>>(xb, W1bT, W3b, W2bT, H1b, AmatT, b1, tW, t);
  phaseCU<<<dim3(512), blk, 0, stream>>>(H1b, W2bT, AmatT, H2b, U, b2);
  phaseD <<<dim3(128), blk, 0, stream>>>(H2b, W3bT, U, dx, ldj, b3);
}

// Round 15
// 110.730 us; speedup vs baseline: 1.4407x; 1.1902x over previous
//
#include <hip/hip_runtime.h>
#include <math.h>

// Problem dims (fixed by setup_inputs): B=1024, D=256, H=1024
#define Bsz 1024
#define Dsz 256
#define Hsz 1024

typedef unsigned short u16;
typedef __bf16 bf16x8 __attribute__((ext_vector_type(8)));
typedef float  f32x4  __attribute__((ext_vector_type(4)));

__device__ __forceinline__ float bf2f(u16 u) {
  unsigned v = ((unsigned)u) << 16;
  return __builtin_bit_cast(float, v);
}
__device__ __forceinline__ u16 f2bf(float f) {
  unsigned u = __builtin_bit_cast(unsigned, f);
  u += 0x7FFFu + ((u >> 16) & 1u);  // round-to-nearest-even
  return (u16)(u >> 16);
}

constexpr int LS = 72;      // LDS row stride (bf16): 144B -> staggered banks
constexpr int TILE = 64 * LS;  // one 64-row tile in LDS (elems)

__device__ __forceinline__ bf16x8 frag(const u16* __restrict__ s, int row, int off) {
  union { uint4 u; bf16x8 b; } cv;
  cv.u = *reinterpret_cast<const uint4*>(&s[row * LS + off]);
  return cv.b;
}
#define MFMA __builtin_amdgcn_mfma_f32_16x16x32_bf16

// ---------------------------------------------------------------------------
// prep: casts/transposes + reg/ldj zeroing (896 blocks)
// ---------------------------------------------------------------------------
__device__ __forceinline__ void cast_chunk(const float* __restrict__ in,
                                           u16* __restrict__ out, int b, int t) {
  const int i = b * 256 + t;
  const float4 v = reinterpret_cast<const float4*>(in)[i];
  ushort4 o;
  o.x = f2bf(v.x); o.y = f2bf(v.y); o.z = f2bf(v.z); o.w = f2bf(v.w);
  *reinterpret_cast<ushort4*>(&out[(size_t)i * 4]) = o;
}

__device__ __forceinline__ void tr_tile(float (*tl)[65], const float* __restrict__ in,
                                        u16* __restrict__ out, int R, int C,
                                        int c0, int r0, int t) {
#pragma unroll
  for (int p = 0; p < 4; ++p) {
    const int r = p * 16 + (t >> 4);
    const int c = (t & 15) * 4;
    const float4 v = *reinterpret_cast<const float4*>(&in[(size_t)(r0 + r) * C + c0 + c]);
    tl[r][c] = v.x; tl[r][c + 1] = v.y; tl[r][c + 2] = v.z; tl[r][c + 3] = v.w;
  }
  __syncthreads();
#pragma unroll
  for (int p = 0; p < 4; ++p) {
    const int a = p * 16 + (t >> 4);
    const int b4 = (t & 15) * 4;
    ushort4 o;
    o.x = f2bf(tl[b4 + 0][a]); o.y = f2bf(tl[b4 + 1][a]);
    o.z = f2bf(tl[b4 + 2][a]); o.w = f2bf(tl[b4 + 3][a]);
    *reinterpret_cast<ushort4*>(&out[(size_t)(c0 + a) * R + r0 + b4]) = o;
  }
}

__global__ __launch_bounds__(256) void prep(const float* __restrict__ x,
                                            const float* __restrict__ W1,
                                            const float* __restrict__ W2,
                                            const float* __restrict__ W3,
                                            u16* __restrict__ xb,
                                            u16* __restrict__ W3b,
                                            u16* __restrict__ W1bT,
                                            u16* __restrict__ W2bT,
                                            u16* __restrict__ W3bT,
                                            float* __restrict__ ldj) {
  __shared__ float tl[64][65];
  const int b = blockIdx.x, t = threadIdx.x;
  if (b == 0) {
    for (int i = t; i < 2048; i += 256) ldj[i] = 0.0f;  // reg must be 0 (ldj stored later)
  }
  if (b < 256) {
    cast_chunk(x, xb, b, t);
  } else if (b < 512) {
    cast_chunk(W3, W3b, b - 256, t);
  } else if (b < 576) {
    const int tb = b - 512;  // W1 [D][H] -> W1bT [H][D]
    tr_tile(tl, W1, W1bT, Dsz, Hsz, (tb & 15) * 64, (tb >> 4) * 64, t);
  } else if (b < 832) {
    const int tb = b - 576;  // W2 [H][H] -> W2bT [H][H]
    tr_tile(tl, W2, W2bT, Hsz, Hsz, (tb & 15) * 64, (tb >> 4) * 64, t);
  } else {
    const int tb = b - 832;  // W3 [H][D] -> W3bT [D][H]
    tr_tile(tl, W3, W3bT, Hsz, Dsz, (tb & 3) * 64, (tb >> 2) * 64, t);
  }
}

// ---------------------------------------------------------------------------
// MFMA GEMM body — 2-phase software pipeline (T3 minimal template):
//   double-buffered LDS, ONE barrier per K-iter, global loads issued right
//   after the barrier so they overlap MFMA compute; store_lds's own vmcnt
//   dependency (not a barrier drain) absorbs residual load latency.
// Old structure stalled a full load-latency at the pre-barrier vmcnt(0)
// drain EVERY iter (m97 barrier-drain effect) — loads were issued
// immediately before a __syncthreads.
// 256 threads = 4 waves in 2x2; each wave a 32x32 quadrant. BK=64.
// SQA: h -> 1-h*h while staging (d1 from H1b without a separate buffer).
// ---------------------------------------------------------------------------
enum { EPI_H1 = 0, EPI_AMAT = 1, EPI_H2 = 2, EPI_DX = 3, EPI_U = 4 };

template <int EPI, bool SQA>
__device__ __forceinline__ void gemm_body(
    int row0, int col0,
    u16* __restrict__ Asb, u16* __restrict__ Bsb,   // each 2*TILE (double buffer)
    const u16* __restrict__ A, const u16* __restrict__ Bt,
    int K, int ldo,
    float* __restrict__ fout, u16* __restrict__ bout,
    const u16* __restrict__ aux,
    const float* __restrict__ v1, const float* __restrict__ v2,
    const float* __restrict__ tptr) {
  const int t = threadIdx.x;
  const int lane = t & 63, wid = t >> 6;

  const int sm = t >> 2, sq = t & 3;
  const size_t a_base = (size_t)(row0 + sm) * K + sq * 8;
  const size_t b_base = (size_t)(col0 + sm) * K + sq * 8;

  uint4 ar[2], br[2];
  auto load_regs = [&](int k0) {
    ar[0] = *reinterpret_cast<const uint4*>(&A[a_base + k0]);
    ar[1] = *reinterpret_cast<const uint4*>(&A[a_base + k0 + 32]);
    br[0] = *reinterpret_cast<const uint4*>(&Bt[b_base + k0]);
    br[1] = *reinterpret_cast<const uint4*>(&Bt[b_base + k0 + 32]);
  };
  auto sq_tr = [&](uint4 v) -> uint4 {
    u16* p = reinterpret_cast<u16*>(&v);
    uint4 o; u16* po = reinterpret_cast<u16*>(&o);
#pragma unroll
    for (int i = 0; i < 8; ++i) { const float h = bf2f(p[i]); po[i] = f2bf(1.0f - h * h); }
    return o;
  };
  auto store_lds = [&](int buf) {
    const int o = buf * TILE + sm * LS + sq * 8;
#pragma unroll
    for (int c = 0; c < 2; ++c) {
      *reinterpret_cast<uint4*>(&Asb[o + c * 32]) = SQA ? sq_tr(ar[c]) : ar[c];
      *reinterpret_cast<uint4*>(&Bsb[o + c * 32]) = br[c];
    }
  };

  f32x4 acc[2][2] = {};
  const int mo = (wid >> 1) * 32, no = (wid & 1) * 32;
  const int fr = lane & 15, fg = lane >> 4;

  const int NK = K >> 6;
  // Prologue: tile 0 into buf 0 (visible to all waves at first barrier).
  load_regs(0);
  store_lds(0);
  int cur = 0;
  for (int it = 0; it < NK; ++it) {
    __syncthreads();                       // buf[cur] visible; buf[cur^1] free
    if (it + 1 < NK) load_regs((it + 1) << 6);  // in flight under compute
    const u16* Ac = Asb + cur * TILE;
    const u16* Bc = Bsb + cur * TILE;
#pragma unroll
    for (int ks = 0; ks < 64; ks += 32) {
      const int off = ks + fg * 8;
      const bf16x8 a0 = frag(Ac, mo + fr, off), a1 = frag(Ac, mo + 16 + fr, off);
      const bf16x8 b0 = frag(Bc, no + fr, off), b1v = frag(Bc, no + 16 + fr, off);
      acc[0][0] = MFMA(a0, b0,  acc[0][0], 0, 0, 0);
      acc[0][1] = MFMA(a0, b1v, acc[0][1], 0, 0, 0);
      acc[1][0] = MFMA(a1, b0,  acc[1][0], 0, 0, 0);
      acc[1][1] = MFMA(a1, b1v, acc[1][1], 0, 0, 0);
    }
    if (it + 1 < NK) store_lds(cur ^ 1);   // waits vmcnt only for its own data
    cur ^= 1;
  }

  // C/D layout (m89-verified): col = lane&15, row = (lane>>4)*4 + reg
  const int cr = mo + fg * 4;  // + mi*16 + r  (block-local row)
  const int cc = no + fr;      // + ni*16      (block-local col)

  if (EPI == EPI_H1) {
    const float ts = tptr[0];
#pragma unroll
    for (int ni = 0; ni < 2; ++ni) {
      const int col = col0 + cc + ni * 16;
      const float add = v1[col] + ts * v2[col];
#pragma unroll
      for (int mi = 0; mi < 2; ++mi)
#pragma unroll
        for (int r = 0; r < 4; ++r) {
          const int row = row0 + cr + mi * 16 + r;
          bout[(size_t)row * Hsz + col] = f2bf(tanhf(acc[mi][ni][r] + add));
        }
    }
  } else if (EPI == EPI_AMAT) {
#pragma unroll
    for (int mi = 0; mi < 2; ++mi)
#pragma unroll
      for (int ni = 0; ni < 2; ++ni)
#pragma unroll
        for (int r = 0; r < 4; ++r) {
          const int row = row0 + cr + mi * 16 + r;
          const int col = col0 + cc + ni * 16;
          const float w2 = bf2f(aux[(size_t)row * Hsz + col]);  // W2bT[j][i] = W2[i][j]
          bout[(size_t)row * Hsz + col] = f2bf(w2 * acc[mi][ni][r]);
        }
  } else if (EPI == EPI_H2) {
#pragma unroll
    for (int ni = 0; ni < 2; ++ni) {
      const int col = col0 + cc + ni * 16;
      const float add = v1[col];
#pragma unroll
      for (int mi = 0; mi < 2; ++mi)
#pragma unroll
        for (int r = 0; r < 4; ++r) {
          const int row = row0 + cr + mi * 16 + r;
          bout[(size_t)row * Hsz + col] = f2bf(tanhf(acc[mi][ni][r] + add));
        }
    }
  } else if (EPI == EPI_DX) {
#pragma unroll
    for (int ni = 0; ni < 2; ++ni) {
      const int col = col0 + cc + ni * 16;
      const float add = v1[col];
#pragma unroll
      for (int mi = 0; mi < 2; ++mi)
#pragma unroll
        for (int r = 0; r < 4; ++r) {
          const int row = row0 + cr + mi * 16 + r;
          fout[(size_t)row * ldo + col] = acc[mi][ni][r] + add;
        }
    }
  } else {  // EPI_U: raw f32 U tile to workspace
#pragma unroll
    for (int ni = 0; ni < 2; ++ni) {
      const int col = col0 + cc + ni * 16;
#pragma unroll
      for (int mi = 0; mi < 2; ++mi)
#pragma unroll
        for (int r = 0; r < 4; ++r) {
          const int row = row0 + cr + mi * 16 + r;
          fout[(size_t)row * Hsz + col] = acc[mi][ni][r];
        }
    }
  }
}

// ---------------------------------------------------------------------------
// Phase B (512 blocks): k1 (b<256) + k2 (b>=256)
// ---------------------------------------------------------------------------
__global__ __launch_bounds__(256) void phaseB(const u16* __restrict__ xb,
                                              const u16* __restrict__ W1bT,
                                              const u16* __restrict__ W3b,
                                              const u16* __restrict__ W2bT,
                                              u16* __restrict__ H1b,
                                              u16* __restrict__ AmatT,
                                              const float* __restrict__ b1,
                                              const float* __restrict__ tW,
                                              const float* __restrict__ t) {
  __shared__ u16 As[2 * TILE];
  __shared__ u16 Bs[2 * TILE];
  const int b = blockIdx.x;
  if (b < 256) {
    gemm_body<EPI_H1, false>((b >> 4) * 64, (b & 15) * 64, As, Bs,
                             xb, W1bT, Dsz, Hsz, nullptr, H1b, nullptr, b1, tW, t);
  } else {
    const int c = b - 256;
    gemm_body<EPI_AMAT, false>((c >> 4) * 64, (c & 15) * 64, As, Bs,
                               W3b, W1bT, Dsz, Hsz, nullptr, AmatT, W2bT,
                               nullptr, nullptr, nullptr);
  }
}

// ---------------------------------------------------------------------------
// Phase CU (512 blocks): k3 H2b=tanh(H1@W2+b2) (b<256)  +  k5a U=d1@Amat
// (b>=256), concurrent (disjoint write sets; both need only phaseB outputs).
// ---------------------------------------------------------------------------
__global__ __launch_bounds__(256) void phaseCU(const u16* __restrict__ H1b,
                                               const u16* __restrict__ W2bT,
                                               const u16* __restrict__ AmatT,
                                               u16* __restrict__ H2b,
                                               float* __restrict__ U,
                                               const float* __restrict__ b2) {
  __shared__ u16 As[2 * TILE];
  __shared__ u16 Bs[2 * TILE];
  const int b = blockIdx.x;
  if (b < 256) {
    gemm_body<EPI_H2, false>((b >> 4) * 64, (b & 15) * 64, As, Bs,
                             H1b, W2bT, Hsz, Hsz, nullptr, H2b, nullptr, b2,
                             nullptr, nullptr);
  } else {
    const int c = b - 256;
    gemm_body<EPI_U, true>((c >> 4) * 64, (c & 15) * 64, As, Bs,
                           H1b, AmatT, Hsz, Hsz, U, nullptr, nullptr,
                           nullptr, nullptr, nullptr);
  }
}

// ---------------------------------------------------------------------------
// Phase D (128 blocks): k4 dx (b<64)  +  k5b masked reduce (b>=64).
// k5b: ldj[row] = sum_j U[row][j] * (1 - h2[row][j]^2), direct store (no
// atomics). 64 blocks x 16 rows; 16 threads/row, coalesced float4 strides.
// ---------------------------------------------------------------------------
__global__ __launch_bounds__(256) void phaseD(const u16* __restrict__ H2b,
                                              const u16* __restrict__ W3bT,
                                              const float* __restrict__ U,
                                              float* __restrict__ dx,
                                              float* __restrict__ ldj,
                                              const float* __restrict__ b3) {
  const int b = blockIdx.x;
  if (b < 64) {
    __shared__ u16 As[2 * TILE];
    __shared__ u16 Bs[2 * TILE];
    gemm_body<EPI_DX, false>((b >> 2) * 64, (b & 3) * 64, As, Bs,
                             H2b, W3bT, Hsz, Dsz, dx, nullptr, nullptr, b3,
                             nullptr, nullptr);
  } else {
    __shared__ float sr[16][17];
    const int t = threadIdx.x;
    const int row = (b - 64) * 16 + (t >> 4);
    const int c0 = (t & 15) * 4;
    float s = 0.0f;
#pragma unroll
    for (int k = 0; k < 16; ++k) {
      const int c = c0 + k * 64;
      const float4 u4 = *reinterpret_cast<const float4*>(&U[(size_t)row * Hsz + c]);
      const ushort4 h4 = *reinterpret_cast<const ushort4*>(&H2b[(size_t)row * Hsz + c]);
      const float h0 = bf2f(h4.x), h1 = bf2f(h4.y), h2 = bf2f(h4.z), h3 = bf2f(h4.w);
      s += u4.x * (1.0f - h0 * h0) + u4.y * (1.0f - h1 * h1)
         + u4.z * (1.0f - h2 * h2) + u4.w * (1.0f - h3 * h3);
    }
    sr[t >> 4][t & 15] = s;
    __syncthreads();
    if (t < 16) {
      float tot = 0.0f;
#pragma unroll
      for (int u = 0; u < 16; ++u) tot += sr[t][u];
      ldj[(b - 64) * 16 + t] = tot;
    }
  }
}

// ---------------------------------------------------------------------------
// Launch: 4 dispatches.
// ldj[b] = sum_{i,j} d1[b,i]*(W2.*N)[i,j]*d2[b,j],  N = (W3@W1)^T.
// AmatT[j][i] = W2[i][j]*(W3@W1)[j][i] is k2's natural tile orientation AND
// the Bt layout k5a consumes.
// ---------------------------------------------------------------------------
extern "C" void kernel_launch(void* const* d_in, const int* in_sizes, int n_in,
                              void* d_out, int out_size, void* d_ws, size_t ws_size,
                              hipStream_t stream) {
  const float* x  = (const float*)d_in[0];
  const float* t  = (const float*)d_in[1];
  const float* W1 = (const float*)d_in[4];
  const float* b1 = (const float*)d_in[5];
  const float* tW = (const float*)d_in[6];
  const float* W2 = (const float*)d_in[7];
  const float* b2 = (const float*)d_in[8];
  const float* W3 = (const float*)d_in[9];
  const float* b3 = (const float*)d_in[10];

  float* out = (float*)d_out;
  float* dx  = out;                      // [B,D]
  float* ldj = out + (size_t)Bsz * Dsz;  // [B], then reg [B]

  u16* w = (u16*)d_ws;
  u16* xb    = w;                    // [B][D]    262144
  u16* W1bT  = xb    + 262144;       // [H][D]    (= W1^T)
  u16* W3b   = W1bT  + 262144;       // [H][D]
  u16* W3bT  = W3b   + 262144;       // [D][H]    (= W3^T)
  u16* W2bT  = W3bT  + 262144;       // [H][H]    (= W2^T)
  u16* AmatT = W2bT  + 1048576;      // [H][H]
  u16* H1b   = AmatT + 1048576;      // [B][H]
  u16* H2b   = H1b   + 1048576;      // [B][H]
  float* U   = (float*)(H2b + 1048576);  // [B][H] f32 (4 MB; 14.5 MB total)

  const dim3 blk(256);
  prep   <<<dim3(896), blk, 0, stream>>>(x, W1, W2, W3, xb, W3b, W1bT, W2bT, W3bT, ldj);
  phaseB <<<dim3(512), blk, 0, stream>>>(xb, W1bT, W3b, W2bT, H1b, AmatT, b1, tW, t);
  phaseCU<<<dim3(512), blk, 0, stream>>>(H1b, W2bT, AmatT, H2b, U, b2);
  phaseD <<<dim3(128), blk, 0, stream>>>(H2b, W3bT, U, dx, ldj, b3);
}